// Round 19
// baseline (202.283 us; speedup 1.0000x reference)
//
#include <hip/hip_runtime.h>
#include <hip/hip_bf16.h>
#include <stdint.h>

#define SEQ 4096
#define HID 1152
#define NH  16
#define HD  72
#define N3  3456
#define DQ  80        // Q padded head dim (5 x 16)
#define QBLK 256      // q rows per block (8 waves x 32)
#define TILE_B 25728  // tile bytes: K 64x256B = 16384, V 73x128B = 9344
#define TILE_E 12864  // tile elems
#define VBASE 16384   // V image byte offset within tile
#define ZOFF  77184   // static 16B zero block (after 3 buffers)

typedef __bf16 bf16;
typedef __bf16 bf16x4 __attribute__((ext_vector_type(4)));
typedef __bf16 bf16x8 __attribute__((ext_vector_type(8)));
typedef float  f32x4  __attribute__((ext_vector_type(4)));
typedef float  f32x16 __attribute__((ext_vector_type(16)));
typedef uint32_t u32x4 __attribute__((ext_vector_type(4)));

#define EXP2F(x) __builtin_amdgcn_exp2f(x)
#define PLSWAP(a, b) asm("v_permlane32_swap_b32 %0, %1" : "+v"(a), "+v"(b))

__device__ __forceinline__ void gload_lds16(const void* g, void* l) {
    __builtin_amdgcn_global_load_lds(
        (__attribute__((address_space(1))) void*)(void*)g,
        (__attribute__((address_space(3))) void*)l, 16, 0, 0);
}
__device__ __forceinline__ uint16_t bfbits(float x) {
    return __builtin_bit_cast(uint16_t, (bf16)x);
}

// ---------------- fused prep: hidden f32->bf16 + wide weight transposes ----------------
// blocks [0,2304): cvt hidden; [2304,3276): Wqkv^T (36x27 tiles of 32r x 128c);
// [3276,3600): Wproj^T (36x9 tiles).
__global__ __launch_bounds__(256)
void prep(const float* __restrict__ hidden, const float* __restrict__ Wqkv,
          const float* __restrict__ Wproj, bf16* __restrict__ hid_b,
          bf16* __restrict__ WqkvT, bf16* __restrict__ WprojT)
{
    __shared__ float tl[32][136];
    int b = blockIdx.x, tid = threadIdx.x;
    if (b < 2304) {
        int i = b * 256 + tid;
        const float4* p = (const float4*)hidden + (size_t)i * 2;
        float4 a = p[0], c = p[1];
        bf16x8 o;
        o[0]=(bf16)a.x; o[1]=(bf16)a.y; o[2]=(bf16)a.z; o[3]=(bf16)a.w;
        o[4]=(bf16)c.x; o[5]=(bf16)c.y; o[6]=(bf16)c.z; o[7]=(bf16)c.w;
        ((bf16x8*)hid_b)[i] = o;
        return;
    }
    const float* in; bf16* out; int R, C, c0, r0;
    if (b < 3276) {
        int bb = b - 2304;                        // 36 x 27
        in = Wqkv; out = WqkvT; R = HID; C = N3;
        r0 = (bb / 27) * 32; c0 = (bb % 27) * 128;
    } else {
        int bb = b - 3276;                        // 36 x 9
        in = Wproj; out = WprojT; R = HID; C = HID;
        r0 = (bb / 9) * 32; c0 = (bb % 9) * 128;
    }
    int tx = tid & 31, ty = tid >> 5;             // float4 col, row group
#pragma unroll
    for (int i = 0; i < 4; ++i) {
        int row = ty + 8 * i;
        float4 v = *(const float4*)&in[(size_t)(r0 + row) * C + c0 + tx * 4];
        *(float4*)&tl[row][tx * 4] = v;
    }
    __syncthreads();
    int cb = tid >> 3, r4 = (tid & 7) * 4;        // 32 col-groups x 8 row-quads
#pragma unroll
    for (int cc = 0; cc < 4; ++cc) {
        int c = cb + cc * 32;
        bf16x4 o;
#pragma unroll
        for (int j = 0; j < 4; ++j) o[j] = (bf16)tl[r4 + j][c];
        *(bf16x4*)&out[(size_t)(c0 + c) * R + r0 + r4] = o;
    }
}

// ---------------- GEMM: C[M][N] = A[M][K] * BT[N][K]^T + bias ----------------
// BK=64, source-baked XOR swizzle; m-stripe-per-XCD mapping (R16 win).
template<int OUT_F32>
__global__ __launch_bounds__(256)
void gemm_bt(const bf16* __restrict__ A, const bf16* __restrict__ BT,
             const float* __restrict__ bias, void* __restrict__ out,
             int M, int N, int K)
{
    __shared__ __align__(16) bf16 As[128 * 64];
    __shared__ __align__(16) bf16 Bs[128 * 64];
    int tid = threadIdx.x;
    int lane = tid & 63, w = tid >> 6;
    int wm = w & 1, wn = w >> 1;
    int orig = blockIdx.y * gridDim.x + blockIdx.x;
    int xcd = orig & 7, v = orig >> 3;
    int mpx = gridDim.x >> 3;
    int m0 = (xcd * mpx + (v % mpx)) * 128;
    int n0 = (v / mpx) * 128;
    int lq = lane & 15, lk = lane >> 4;

    int kx0 = ((lk ^ (lq & 7)) << 4);
    int kx1 = (((4 + lk) ^ (lq & 7)) << 4);

    f32x4 acc[4][4] = {};

    for (int k0 = 0; k0 < K; k0 += 64) {
        __syncthreads();
#pragma unroll
        for (int j = 0; j < 4; ++j) {
            int c = j * 256 + tid;
            int row = c >> 3, kc = c & 7;
            int koff = k0 + ((kc ^ (row & 7)) << 3);
            gload_lds16(A  + (size_t)(m0 + row) * K + koff, (char*)As + c * 16);
            gload_lds16(BT + (size_t)(n0 + row) * K + koff, (char*)Bs + c * 16);
        }
        __syncthreads();
#pragma unroll
        for (int ks = 0; ks < 2; ++ks) {
            int kx = ks ? kx1 : kx0;
            bf16x8 af[4], bfr[4];
#pragma unroll
            for (int m = 0; m < 4; ++m)
                af[m] = *(const bf16x8*)((char*)As + (wm * 64 + m * 16 + lq) * 128 + kx);
#pragma unroll
            for (int n = 0; n < 4; ++n)
                bfr[n] = *(const bf16x8*)((char*)Bs + (wn * 64 + n * 16 + lq) * 128 + kx);
#pragma unroll
            for (int m = 0; m < 4; ++m)
#pragma unroll
                for (int n = 0; n < 4; ++n)
                    acc[m][n] = __builtin_amdgcn_mfma_f32_16x16x32_bf16(af[m], bfr[n], acc[m][n], 0, 0, 0);
        }
    }

    int rb = m0 + wm * 64, cb = n0 + wn * 64;
#pragma unroll
    for (int m = 0; m < 4; ++m) {
#pragma unroll
        for (int n = 0; n < 4; ++n) {
            int col = cb + n * 16 + lq;
            float b = bias[col];
#pragma unroll
            for (int r = 0; r < 4; ++r) {
                int row = rb + m * 16 + lk * 4 + r;
                float v2 = acc[m][n][r] + b;
                if (OUT_F32) ((float*)out)[(size_t)row * N + col] = v2;
                else         ((bf16*)out)[(size_t)row * N + col] = (bf16)v2;
            }
        }
    }
}

// ---------------- fused pack: RoPE Q/K + V-transpose into KVp tile images ----------------
// blocks [0,32768): rope over NH*SEQ*128; [32768,33792): V pack.
// KVp[h][t][12864]: elems 0..8191 = K image, 64 keys x 128 elems (256B rows),
// chunk pos = dchunk ^ (key&15), dchunk 0..15 (dims 80..127 zero).
// elems 8192..12863 = V image, 73 rows x 64 elems (d 0..71 data, 72 = ones);
// storage pos cpos holds keys (cpos^(d&7))*8..
__global__ __launch_bounds__(256)
void pack(const bf16* __restrict__ qkv, const float* __restrict__ cs,
          const float* __restrict__ sn, bf16* __restrict__ Qp,
          bf16* __restrict__ KVp)
{
    __shared__ __align__(16) bf16 tl[64][80];
    int b = blockIdx.x, tid = threadIdx.x;
    if (b < 32768) {
        int idx = b * 256 + tid;                 // NH*SEQ*128
        int dd = idx & 127;
        int s  = (idx >> 7) & (SEQ - 1);
        int h  = idx >> 19;
        float qv = 0.f, kv = 0.f;
        if (dd < HD) {
            const bf16* row = qkv + (size_t)s * N3 + h * HD;
            float c  = cs[s * HD + dd], si = sn[s * HD + dd];
            int   dp = (dd < 36) ? dd + 36 : dd - 36;
            float sg = (dd < 36) ? -1.f : 1.f;
            float qa = (float)row[dd],       qb = (float)row[dp];
            float ka = (float)row[HID + dd], kb = (float)row[HID + dp];
            qv = (qa * c + sg * qb * si) * (0.11785113019775793f * 1.4426950408889634f);
            kv =  ka * c + sg * kb * si;
        }
        int t = s >> 6, key = s & 63;
        int chunk = key * 16 + ((dd >> 3) ^ (key & 15));
        KVp[((size_t)(h * 64 + t)) * TILE_E + chunk * 8 + (dd & 7)] = (bf16)kv;
        if (dd < DQ) Qp[((size_t)h * SEQ + s) * DQ + dd] = (bf16)qv;
        return;
    }
    int bb = b - 32768;
    int t = bb & 63, h = bb >> 6, s0 = t * 64;
    for (int i = tid; i < 64 * 9; i += 256) {
        int key = i / 9, c8 = (i % 9) * 8;
        *(bf16x8*)&tl[key][c8] =
            *(const bf16x8*)&qkv[(size_t)(s0 + key) * N3 + 2 * HID + h * HD + c8];
    }
    __syncthreads();
    bf16* dst = KVp + ((size_t)(h * 64 + t)) * TILE_E + 8192;
    for (int vcid = tid; vcid < 584; vcid += 256) {     // 73 rows x 8 chunks
        int d = vcid >> 3, cpos = vcid & 7;
        int kb8 = (cpos ^ (d & 7)) << 3;
        bf16x8 v;
#pragma unroll
        for (int j = 0; j < 8; ++j)
            v[j] = (d < HD) ? tl[kb8 + j][d] : (bf16)1.f;   // d==72: ones row
        *(bf16x8*)&dst[vcid * 8] = v;
    }
}

// ---- flash attention: 8 waves x 32q, 3-buffer rotation ----
// K image: R13's 256B rows + span-16 swizzle (6.3M-conflict layout -- R18's
// span-8 trim raised conflicts to 10M, reverted). V: trimmed 73 rows with
// static-zero redirect for PV db=2 pad lanes (kept from R18).
__global__ __launch_bounds__(512, 2)
void attn_fwd14(const bf16* __restrict__ Qp, const bf16* __restrict__ KVp,
                bf16* __restrict__ Oout)
{
    __shared__ __align__(16) char smem[77312];   // 3 x 25728 + zero block

    const int o = blockIdx.x;
    const int x = o & 7, s = o >> 3;
    const int h  = x * 2 + (s >> 4);
    const int q0 = (s & 15) * QBLK;
    const int tid = threadIdx.x, lane = tid & 63, w = tid >> 6;
    const int ql = lane & 31, hi = lane >> 5;
    const int q  = q0 + w * 32 + ql;

    bf16x8 qf[5];
    const bf16* qbase = Qp + ((size_t)h * SEQ + q) * DQ + hi * 8;
#pragma unroll
    for (int ks = 0; ks < 5; ++ks) qf[ks] = *(const bf16x8*)(qbase + ks * 16);

    // K offsets: 256B rows, span-16 swizzle (uses ql bit3 -> breaks a-group aliasing)
    int aK[5];
#pragma unroll
    for (int ks = 0; ks < 5; ++ks)
        aK[ks] = ql * 256 + (((ks * 2 + hi) ^ (ql & 15)) * 16);
    // V offsets (rows = db*32+ql within 73-row image at VBASE)
    int aV[4];
#pragma unroll
    for (int u = 0; u < 4; ++u)
        aV[u] = VBASE + ql * 128 + (((u * 2 + hi) ^ (ql & 7)) * 16);

    f32x16 o_[3] = {};           // O^T accum; V row 72 (ones) carries l

    const bf16* kvh = KVp + (size_t)h * (64 * TILE_E);

#define STAGE(T, DB) do {                                                      \
        const bf16* s_ = kvh + (size_t)(T) * TILE_E;                           \
        _Pragma("unroll")                                                      \
        for (int j_ = 0; j_ < 4; ++j_) {                                       \
            int c_ = j_ * 512 + tid;                                           \
            if (c_ < 1608) gload_lds16(s_ + c_ * 8, smem + (DB) + c_ * 16);    \
        }                                                                      \
    } while (0)

    auto qk = [&](const char* bK, f32x16& sa, f32x16& sb) {
        __builtin_amdgcn_s_setprio(1);
#pragma unroll
        for (int ks = 0; ks < 5; ++ks) {
            bf16x8 kf = *(const bf16x8*)(bK + aK[ks]);
            sa = __builtin_amdgcn_mfma_f32_32x32x16_bf16(kf, qf[ks], sa, 0, 0, 0);
        }
#pragma unroll
        for (int ks = 0; ks < 5; ++ks) {
            bf16x8 kf = *(const bf16x8*)(bK + 8192 + aK[ks]);   // keys 32..63
            sb = __builtin_amdgcn_mfma_f32_32x32x16_bf16(kf, qf[ks], sb, 0, 0, 0);
        }
        __builtin_amdgcn_s_setprio(0);
    };

    auto expv = [&](const f32x16& sa, const f32x16& sb, const char* bV) {
        uint32_t wd[16];
#pragma unroll
        for (int i = 0; i < 8; ++i) {
            wd[i]   = (uint32_t)bfbits(EXP2F(sa[2*i])) | ((uint32_t)bfbits(EXP2F(sa[2*i+1])) << 16);
            wd[8+i] = (uint32_t)bfbits(EXP2F(sb[2*i])) | ((uint32_t)bfbits(EXP2F(sb[2*i+1])) << 16);
        }
        PLSWAP(wd[0], wd[2]);   PLSWAP(wd[1], wd[3]);
        PLSWAP(wd[4], wd[6]);   PLSWAP(wd[5], wd[7]);
        PLSWAP(wd[8], wd[10]);  PLSWAP(wd[9], wd[11]);
        PLSWAP(wd[12], wd[14]); PLSWAP(wd[13], wd[15]);
        u32x4 u0 = {wd[0],wd[1],wd[2],wd[3]},   u1 = {wd[4],wd[5],wd[6],wd[7]};
        u32x4 u2 = {wd[8],wd[9],wd[10],wd[11]}, u3 = {wd[12],wd[13],wd[14],wd[15]};
        bf16x8 pb[4] = { __builtin_bit_cast(bf16x8, u0), __builtin_bit_cast(bf16x8, u1),
                         __builtin_bit_cast(bf16x8, u2), __builtin_bit_cast(bf16x8, u3) };
        __builtin_amdgcn_s_setprio(1);
#pragma unroll
        for (int db = 0; db < 3; ++db)
#pragma unroll
            for (int u = 0; u < 4; ++u) {
                const char* pv;
                if (db < 2)          pv = bV + db * 4096 + aV[u];
                else if (ql <= 8)    pv = bV + 8192 + aV[u];      // rows 64..72
                else                 pv = smem + ZOFF;            // zero pad rows
                bf16x8 vf = *(const bf16x8*)pv;
                o_[db] = __builtin_amdgcn_mfma_f32_32x32x16_bf16(vf, pb[u], o_[db], 0, 0, 0);
            }
        __builtin_amdgcn_s_setprio(0);
    };

    f32x16 pa = {}, pb_ = {};    // previous tile's scores (pipeline state)

    if (tid < 4) ((float*)(smem + ZOFF))[tid] = 0.f;
    STAGE(0, 0);
    asm volatile("s_waitcnt vmcnt(0) lgkmcnt(0)" ::: "memory");
    __builtin_amdgcn_s_barrier();
    STAGE(1, TILE_B);
    qk(smem, pa, pb_);
    asm volatile("s_waitcnt vmcnt(0)" ::: "memory");
    __builtin_amdgcn_s_barrier();

#define BODY(T, KB, VB, SB) do {                                               \
        if ((T) < 63) STAGE((T) + 1, SB);                                      \
        f32x16 ca = {}, cb = {};                                               \
        qk(smem + (KB), ca, cb);                                               \
        expv(pa, pb_, smem + (VB));                                            \
        pa = ca; pb_ = cb;                                                     \
        __builtin_amdgcn_sched_barrier(0);                                     \
        asm volatile("s_waitcnt vmcnt(0)" ::: "memory");                       \
        __builtin_amdgcn_s_barrier();                                          \
    } while (0)

    for (int t = 1; t < 64; t += 3) {
        BODY(t,     TILE_B,     0,          2 * TILE_B);
        BODY(t + 1, 2 * TILE_B, TILE_B,     0);
        BODY(t + 2, 0,          2 * TILE_B, TILE_B);
    }
    expv(pa, pb_, smem);         // drain: tile 63 (V resident in buffer 0)
#undef BODY
#undef STAGE

    // ---- epilogue: LDS transpose (stride 82 = 41 words, odd -> conflict-free) ----
    __syncthreads();
    bf16* Os = (bf16*)smem;                        // [QBLK][82]
    {
        float lv  = o_[2][4];                      // d=72 row holds l (hi=0 lanes)
        float lo_ = __shfl_xor(lv, 32);
        float invl = 1.0f / (hi ? lo_ : lv);
        int qloc = w * 32 + ql;
#pragma unroll
        for (int db = 0; db < 3; ++db)
#pragma unroll
            for (int r = 0; r < 16; ++r) {
                int dloc = (r & 3) + 8 * (r >> 2) + 4 * hi;
                int d = db * 32 + dloc;
                if (d < HD) Os[qloc * 82 + d] = (bf16)(o_[db][r] * invl);
            }
    }
    __syncthreads();
    for (int i = tid; i < QBLK * 36; i += 512) {
        int row = i / 36, c = i % 36;
        uint32_t val = *(const uint32_t*)((const char*)Os + row * 164 + c * 4);
        *(uint32_t*)((char*)Oout + (size_t)(q0 + row) * 2304 + h * 144 + c * 4) = val;
    }
}

extern "C" void kernel_launch(void* const* d_in, const int* in_sizes, int n_in,
                              void* d_out, int out_size, void* d_ws, size_t ws_size,
                              hipStream_t stream)
{
    const float* hidden = (const float*)d_in[0];
    // d_in[1] = cu_seqlens: unused by the reference
    const float* cosT  = (const float*)d_in[2];
    const float* sinT  = (const float*)d_in[3];
    const float* Wqkv  = (const float*)d_in[4];
    const float* bqkv  = (const float*)d_in[5];
    const float* Wproj = (const float*)d_in[6];
    const float* bproj = (const float*)d_in[7];

    char* ws = (char*)d_ws;
    size_t off = 0;
    auto alloc = [&](size_t bytes) {
        char* p = ws + off;
        off += (bytes + 255) & ~(size_t)255;
        return p;
    };
    bf16* hid_b  = (bf16*)alloc((size_t)SEQ * HID * 2);
    bf16* WqkvT  = (bf16*)alloc((size_t)N3  * HID * 2);
    bf16* WprojT = (bf16*)alloc((size_t)HID * HID * 2);
    bf16* qkv_b  = (bf16*)alloc((size_t)SEQ * N3  * 2);
    bf16* Qp     = (bf16*)alloc((size_t)NH * SEQ * DQ * 2);
    bf16* KVp    = (bf16*)alloc((size_t)NH * 64 * TILE_E * 2);
    bf16* attno  = hid_b;  // overlay: hid_b dead after GEMM1

    prep<<<3600, 256, 0, stream>>>(hidden, Wqkv, Wproj, hid_b, WqkvT, WprojT);
    gemm_bt<0><<<dim3(SEQ / 128, N3 / 128), 256, 0, stream>>>(hid_b, WqkvT, bqkv, qkv_b,
                                                              SEQ, N3, HID);
    pack<<<33792, 256, 0, stream>>>(qkv_b, cosT, sinT, Qp, KVp);
    attn_fwd14<<<dim3(SEQ / QBLK * NH), 512, 0, stream>>>(Qp, KVp, attno);
    gemm_bt<1><<<dim3(SEQ / 128, HID / 128), 256, 0, stream>>>(attno, WprojT, bproj, d_out,
                                                               SEQ, HID, HID);
}

// Round 20
// 196.600 us; speedup vs baseline: 1.0289x; 1.0289x over previous
//
#include <hip/hip_runtime.h>
#include <hip/hip_bf16.h>
#include <stdint.h>

#define SEQ 4096
#define HID 1152
#define NH  16
#define HD  72
#define N3  3456
#define DQ  80        // Q padded head dim (5 x 16)
#define QBLK 256      // q rows per block (8 waves x 32)
#define TILE_B 25728  // tile bytes: K 64x256B = 16384, V 73x128B = 9344
#define TILE_E 12864  // tile elems
#define VBASE 16384   // V image byte offset within tile
#define ZOFF  77184   // static 16B zero block (after 3 buffers)

typedef __bf16 bf16;
typedef __bf16 bf16x8 __attribute__((ext_vector_type(8)));
typedef float  f32x4  __attribute__((ext_vector_type(4)));
typedef float  f32x16 __attribute__((ext_vector_type(16)));
typedef uint32_t u32x4 __attribute__((ext_vector_type(4)));

#define EXP2F(x) __builtin_amdgcn_exp2f(x)
#define PLSWAP(a, b) asm("v_permlane32_swap_b32 %0, %1" : "+v"(a), "+v"(b))

__device__ __forceinline__ void gload_lds16(const void* g, void* l) {
    __builtin_amdgcn_global_load_lds(
        (__attribute__((address_space(1))) void*)(void*)g,
        (__attribute__((address_space(3))) void*)l, 16, 0, 0);
}
__device__ __forceinline__ uint16_t bfbits(float x) {
    return __builtin_bit_cast(uint16_t, (bf16)x);
}

// ---------------- fused prep: hidden f32->bf16 + both weight transposes ----------------
// (R18's proven version) blocks [0,2304): cvt; [2304,6192): Wqkv^T; [6192,7488): Wproj^T
__global__ __launch_bounds__(256)
void prep(const float* __restrict__ hidden, const float* __restrict__ Wqkv,
          const float* __restrict__ Wproj, bf16* __restrict__ hid_b,
          bf16* __restrict__ WqkvT, bf16* __restrict__ WprojT)
{
    __shared__ float tl[32][33];
    int b = blockIdx.x, tid = threadIdx.x;
    if (b < 2304) {
        int i = b * 256 + tid;
        const float4* p = (const float4*)hidden + (size_t)i * 2;
        float4 a = p[0], c = p[1];
        bf16x8 o;
        o[0]=(bf16)a.x; o[1]=(bf16)a.y; o[2]=(bf16)a.z; o[3]=(bf16)a.w;
        o[4]=(bf16)c.x; o[5]=(bf16)c.y; o[6]=(bf16)c.z; o[7]=(bf16)c.w;
        ((bf16x8*)hid_b)[i] = o;
        return;
    }
    const float* in; bf16* out; int R, C, c0, r0;
    if (b < 6192) {
        int bb = b - 2304;
        in = Wqkv; out = WqkvT; R = HID; C = N3;
        c0 = (bb % 108) * 32; r0 = (bb / 108) * 32;
    } else {
        int bb = b - 6192;
        in = Wproj; out = WprojT; R = HID; C = HID;
        c0 = (bb % 36) * 32; r0 = (bb / 36) * 32;
    }
    int tx = tid & 31, ty = tid >> 5;
#pragma unroll
    for (int i = 0; i < 4; ++i)
        tl[ty + 8*i][tx] = in[(size_t)(r0 + ty + 8*i) * C + c0 + tx];
    __syncthreads();
#pragma unroll
    for (int i = 0; i < 4; ++i)
        out[(size_t)(c0 + ty + 8*i) * R + r0 + tx] = (bf16)tl[tx][ty + 8*i];
}

// ---------------- GEMM: C[M][N] = A[M][K] * BT[N][K]^T + bias ----------------
// BK=64, source-baked XOR swizzle; m-stripe-per-XCD mapping (R16 win).
template<int OUT_F32>
__global__ __launch_bounds__(256)
void gemm_bt(const bf16* __restrict__ A, const bf16* __restrict__ BT,
             const float* __restrict__ bias, void* __restrict__ out,
             int M, int N, int K)
{
    __shared__ __align__(16) bf16 As[128 * 64];
    __shared__ __align__(16) bf16 Bs[128 * 64];
    int tid = threadIdx.x;
    int lane = tid & 63, w = tid >> 6;
    int wm = w & 1, wn = w >> 1;
    int orig = blockIdx.y * gridDim.x + blockIdx.x;
    int xcd = orig & 7, v = orig >> 3;
    int mpx = gridDim.x >> 3;
    int m0 = (xcd * mpx + (v % mpx)) * 128;
    int n0 = (v / mpx) * 128;
    int lq = lane & 15, lk = lane >> 4;

    int kx0 = ((lk ^ (lq & 7)) << 4);
    int kx1 = (((4 + lk) ^ (lq & 7)) << 4);

    f32x4 acc[4][4] = {};

    for (int k0 = 0; k0 < K; k0 += 64) {
        __syncthreads();
#pragma unroll
        for (int j = 0; j < 4; ++j) {
            int c = j * 256 + tid;
            int row = c >> 3, kc = c & 7;
            int koff = k0 + ((kc ^ (row & 7)) << 3);
            gload_lds16(A  + (size_t)(m0 + row) * K + koff, (char*)As + c * 16);
            gload_lds16(BT + (size_t)(n0 + row) * K + koff, (char*)Bs + c * 16);
        }
        __syncthreads();
#pragma unroll
        for (int ks = 0; ks < 2; ++ks) {
            int kx = ks ? kx1 : kx0;
            bf16x8 af[4], bfr[4];
#pragma unroll
            for (int m = 0; m < 4; ++m)
                af[m] = *(const bf16x8*)((char*)As + (wm * 64 + m * 16 + lq) * 128 + kx);
#pragma unroll
            for (int n = 0; n < 4; ++n)
                bfr[n] = *(const bf16x8*)((char*)Bs + (wn * 64 + n * 16 + lq) * 128 + kx);
#pragma unroll
            for (int m = 0; m < 4; ++m)
#pragma unroll
                for (int n = 0; n < 4; ++n)
                    acc[m][n] = __builtin_amdgcn_mfma_f32_16x16x32_bf16(af[m], bfr[n], acc[m][n], 0, 0, 0);
        }
    }

    int rb = m0 + wm * 64, cb = n0 + wn * 64;
#pragma unroll
    for (int m = 0; m < 4; ++m) {
#pragma unroll
        for (int n = 0; n < 4; ++n) {
            int col = cb + n * 16 + lq;
            float b = bias[col];
#pragma unroll
            for (int r = 0; r < 4; ++r) {
                int row = rb + m * 16 + lk * 4 + r;
                float v2 = acc[m][n][r] + b;
                if (OUT_F32) ((float*)out)[(size_t)row * N + col] = v2;
                else         ((bf16*)out)[(size_t)row * N + col] = (bf16)v2;
            }
        }
    }
}

// ---------------- fused pack: RoPE Q/K + V-transpose into KVp tile images ----------------
// blocks [0,20480): rope over NH*SEQ*80; [20480,21504): V pack.
// KVp[h][t][12864]: elems 0..8191 = K image, 64 keys x 128 elems (256B rows),
// data chunk dchunk (0..9) at physical pos dchunk^(key&15). The 6 remaining
// positions per row are NEVER read by attn (reader's logical chunks are 0..9),
// so they are left unwritten. elems 8192..12863 = V image, 73 rows x 64 elems
// (d 0..71 data, 72 = ones for l); storage pos cpos holds keys (cpos^(d&7))*8..
__global__ __launch_bounds__(256)
void pack(const bf16* __restrict__ qkv, const float* __restrict__ cs,
          const float* __restrict__ sn, bf16* __restrict__ Qp,
          bf16* __restrict__ KVp)
{
    __shared__ __align__(16) bf16 tl[64][80];
    int b = blockIdx.x, tid = threadIdx.x;
    if (b < 20480) {
        int idx = b * 256 + tid;                 // NH*SEQ*80
        int dd = idx % 80;
        int rest = idx / 80;
        int s = rest & (SEQ - 1), h = rest >> 12;
        float qv = 0.f, kv = 0.f;
        if (dd < HD) {
            const bf16* row = qkv + (size_t)s * N3 + h * HD;
            float c  = cs[s * HD + dd], si = sn[s * HD + dd];
            int   dp = (dd < 36) ? dd + 36 : dd - 36;
            float sg = (dd < 36) ? -1.f : 1.f;
            float qa = (float)row[dd],       qb = (float)row[dp];
            float ka = (float)row[HID + dd], kb = (float)row[HID + dp];
            qv = (qa * c + sg * qb * si) * (0.11785113019775793f * 1.4426950408889634f);
            kv =  ka * c + sg * kb * si;
        }
        int t = s >> 6, key = s & 63;
        int chunk = key * 16 + ((dd >> 3) ^ (key & 15));
        KVp[((size_t)(h * 64 + t)) * TILE_E + chunk * 8 + (dd & 7)] = (bf16)kv;
        Qp[((size_t)h * SEQ + s) * DQ + dd] = (bf16)qv;
        return;
    }
    int bb = b - 20480;
    int t = bb & 63, h = bb >> 6, s0 = t * 64;
    for (int i = tid; i < 64 * 9; i += 256) {
        int key = i / 9, c8 = (i % 9) * 8;
        *(bf16x8*)&tl[key][c8] =
            *(const bf16x8*)&qkv[(size_t)(s0 + key) * N3 + 2 * HID + h * HD + c8];
    }
    __syncthreads();
    bf16* dst = KVp + ((size_t)(h * 64 + t)) * TILE_E + 8192;
    for (int vcid = tid; vcid < 584; vcid += 256) {     // 73 rows x 8 chunks
        int d = vcid >> 3, cpos = vcid & 7;
        int kb8 = (cpos ^ (d & 7)) << 3;
        bf16x8 v;
#pragma unroll
        for (int j = 0; j < 8; ++j)
            v[j] = (d < HD) ? tl[kb8 + j][d] : (bf16)1.f;   // d==72: ones row
        *(bf16x8*)&dst[vcid * 8] = v;
    }
}

// ---- flash attention: 8 waves x 32q, 3-buffer rotation (R19's attn_fwd14) ----
// K: 256B rows + span-16 swizzle (4.8M-conflict best). V: 73 rows + static-zero
// redirect for PV db=2 pad lanes. No-max softmax; l via ones-row of V.
__global__ __launch_bounds__(512, 2)
void attn_fwd14(const bf16* __restrict__ Qp, const bf16* __restrict__ KVp,
                bf16* __restrict__ Oout)
{
    __shared__ __align__(16) char smem[77312];   // 3 x 25728 + zero block

    const int o = blockIdx.x;
    const int x = o & 7, s = o >> 3;
    const int h  = x * 2 + (s >> 4);
    const int q0 = (s & 15) * QBLK;
    const int tid = threadIdx.x, lane = tid & 63, w = tid >> 6;
    const int ql = lane & 31, hi = lane >> 5;
    const int q  = q0 + w * 32 + ql;

    bf16x8 qf[5];
    const bf16* qbase = Qp + ((size_t)h * SEQ + q) * DQ + hi * 8;
#pragma unroll
    for (int ks = 0; ks < 5; ++ks) qf[ks] = *(const bf16x8*)(qbase + ks * 16);

    int aK[5];
#pragma unroll
    for (int ks = 0; ks < 5; ++ks)
        aK[ks] = ql * 256 + (((ks * 2 + hi) ^ (ql & 15)) * 16);
    int aV[4];
#pragma unroll
    for (int u = 0; u < 4; ++u)
        aV[u] = VBASE + ql * 128 + (((u * 2 + hi) ^ (ql & 7)) * 16);

    f32x16 o_[3] = {};           // O^T accum; V row 72 (ones) carries l

    const bf16* kvh = KVp + (size_t)h * (64 * TILE_E);

#define STAGE(T, DB) do {                                                      \
        const bf16* s_ = kvh + (size_t)(T) * TILE_E;                           \
        _Pragma("unroll")                                                      \
        for (int j_ = 0; j_ < 4; ++j_) {                                       \
            int c_ = j_ * 512 + tid;                                           \
            if (c_ < 1608) gload_lds16(s_ + c_ * 8, smem + (DB) + c_ * 16);    \
        }                                                                      \
    } while (0)

    auto qk = [&](const char* bK, f32x16& sa, f32x16& sb) {
        __builtin_amdgcn_s_setprio(1);
#pragma unroll
        for (int ks = 0; ks < 5; ++ks) {
            bf16x8 kf = *(const bf16x8*)(bK + aK[ks]);
            sa = __builtin_amdgcn_mfma_f32_32x32x16_bf16(kf, qf[ks], sa, 0, 0, 0);
        }
#pragma unroll
        for (int ks = 0; ks < 5; ++ks) {
            bf16x8 kf = *(const bf16x8*)(bK + 8192 + aK[ks]);   // keys 32..63
            sb = __builtin_amdgcn_mfma_f32_32x32x16_bf16(kf, qf[ks], sb, 0, 0, 0);
        }
        __builtin_amdgcn_s_setprio(0);
    };

    auto expv = [&](const f32x16& sa, const f32x16& sb, const char* bV) {
        uint32_t wd[16];
#pragma unroll
        for (int i = 0; i < 8; ++i) {
            wd[i]   = (uint32_t)bfbits(EXP2F(sa[2*i])) | ((uint32_t)bfbits(EXP2F(sa[2*i+1])) << 16);
            wd[8+i] = (uint32_t)bfbits(EXP2F(sb[2*i])) | ((uint32_t)bfbits(EXP2F(sb[2*i+1])) << 16);
        }
        PLSWAP(wd[0], wd[2]);   PLSWAP(wd[1], wd[3]);
        PLSWAP(wd[4], wd[6]);   PLSWAP(wd[5], wd[7]);
        PLSWAP(wd[8], wd[10]);  PLSWAP(wd[9], wd[11]);
        PLSWAP(wd[12], wd[14]); PLSWAP(wd[13], wd[15]);
        u32x4 u0 = {wd[0],wd[1],wd[2],wd[3]},   u1 = {wd[4],wd[5],wd[6],wd[7]};
        u32x4 u2 = {wd[8],wd[9],wd[10],wd[11]}, u3 = {wd[12],wd[13],wd[14],wd[15]};
        bf16x8 pb[4] = { __builtin_bit_cast(bf16x8, u0), __builtin_bit_cast(bf16x8, u1),
                         __builtin_bit_cast(bf16x8, u2), __builtin_bit_cast(bf16x8, u3) };
        __builtin_amdgcn_s_setprio(1);
#pragma unroll
        for (int db = 0; db < 3; ++db)
#pragma unroll
            for (int u = 0; u < 4; ++u) {
                const char* pv;
                if (db < 2)          pv = bV + db * 4096 + aV[u];
                else if (ql <= 8)    pv = bV + 8192 + aV[u];      // rows 64..72
                else                 pv = smem + ZOFF;            // zero pad rows
                bf16x8 vf = *(const bf16x8*)pv;
                o_[db] = __builtin_amdgcn_mfma_f32_32x32x16_bf16(vf, pb[u], o_[db], 0, 0, 0);
            }
        __builtin_amdgcn_s_setprio(0);
    };

    f32x16 pa = {}, pb_ = {};    // previous tile's scores (pipeline state)

    if (tid < 4) ((float*)(smem + ZOFF))[tid] = 0.f;
    STAGE(0, 0);
    asm volatile("s_waitcnt vmcnt(0) lgkmcnt(0)" ::: "memory");
    __builtin_amdgcn_s_barrier();
    STAGE(1, TILE_B);
    qk(smem, pa, pb_);
    asm volatile("s_waitcnt vmcnt(0)" ::: "memory");
    __builtin_amdgcn_s_barrier();

#define BODY(T, KB, VB, SB) do {                                               \
        if ((T) < 63) STAGE((T) + 1, SB);                                      \
        f32x16 ca = {}, cb = {};                                               \
        qk(smem + (KB), ca, cb);                                               \
        expv(pa, pb_, smem + (VB));                                            \
        pa = ca; pb_ = cb;                                                     \
        __builtin_amdgcn_sched_barrier(0);                                     \
        asm volatile("s_waitcnt vmcnt(0)" ::: "memory");                       \
        __builtin_amdgcn_s_barrier();                                          \
    } while (0)

    for (int t = 1; t < 64; t += 3) {
        BODY(t,     TILE_B,     0,          2 * TILE_B);
        BODY(t + 1, 2 * TILE_B, TILE_B,     0);
        BODY(t + 2, 0,          2 * TILE_B, TILE_B);
    }
    expv(pa, pb_, smem);         // drain: tile 63 (V resident in buffer 0)
#undef BODY
#undef STAGE

    // ---- epilogue: LDS transpose (stride 82 = 41 words, odd -> conflict-free) ----
    __syncthreads();
    bf16* Os = (bf16*)smem;                        // [QBLK][82]
    {
        float lv  = o_[2][4];                      // d=72 row holds l (hi=0 lanes)
        float lo_ = __shfl_xor(lv, 32);
        float invl = 1.0f / (hi ? lo_ : lv);
        int qloc = w * 32 + ql;
#pragma unroll
        for (int db = 0; db < 3; ++db)
#pragma unroll
            for (int r = 0; r < 16; ++r) {
                int dloc = (r & 3) + 8 * (r >> 2) + 4 * hi;
                int d = db * 32 + dloc;
                if (d < HD) Os[qloc * 82 + d] = (bf16)(o_[db][r] * invl);
            }
    }
    __syncthreads();
    for (int i = tid; i < QBLK * 36; i += 512) {
        int row = i / 36, c = i % 36;
        uint32_t val = *(const uint32_t*)((const char*)Os + row * 164 + c * 4);
        *(uint32_t*)((char*)Oout + (size_t)(q0 + row) * 2304 + h * 144 + c * 4) = val;
    }
}

extern "C" void kernel_launch(void* const* d_in, const int* in_sizes, int n_in,
                              void* d_out, int out_size, void* d_ws, size_t ws_size,
                              hipStream_t stream)
{
    const float* hidden = (const float*)d_in[0];
    // d_in[1] = cu_seqlens: unused by the reference
    const float* cosT  = (const float*)d_in[2];
    const float* sinT  = (const float*)d_in[3];
    const float* Wqkv  = (const float*)d_in[4];
    const float* bqkv  = (const float*)d_in[5];
    const float* Wproj = (const float*)d_in[6];
    const float* bproj = (const float*)d_in[7];

    char* ws = (char*)d_ws;
    size_t off = 0;
    auto alloc = [&](size_t bytes) {
        char* p = ws + off;
        off += (bytes + 255) & ~(size_t)255;
        return p;
    };
    bf16* hid_b  = (bf16*)alloc((size_t)SEQ * HID * 2);
    bf16* WqkvT  = (bf16*)alloc((size_t)N3  * HID * 2);
    bf16* WprojT = (bf16*)alloc((size_t)HID * HID * 2);
    bf16* qkv_b  = (bf16*)alloc((size_t)SEQ * N3  * 2);
    bf16* Qp     = (bf16*)alloc((size_t)NH * SEQ * DQ * 2);
    bf16* KVp    = (bf16*)alloc((size_t)NH * 64 * TILE_E * 2);
    bf16* attno  = hid_b;  // overlay: hid_b dead after GEMM1

    prep<<<7488, 256, 0, stream>>>(hidden, Wqkv, Wproj, hid_b, WqkvT, WprojT);
    gemm_bt<0><<<dim3(SEQ / 128, N3 / 128), 256, 0, stream>>>(hid_b, WqkvT, bqkv, qkv_b,
                                                              SEQ, N3, HID);
    pack<<<21504, 256, 0, stream>>>(qkv_b, cosT, sinT, Qp, KVp);
    attn_fwd14<<<dim3(SEQ / QBLK * NH), 512, 0, stream>>>(Qp, KVp, attno);
    gemm_bt<1><<<dim3(SEQ / 128, HID / 128), 256, 0, stream>>>(attno, WprojT, bproj, d_out,
                                                               SEQ, HID, HID);
}

// Round 21
// 184.456 us; speedup vs baseline: 1.0966x; 1.0658x over previous
//
#include <hip/hip_runtime.h>
#include <hip/hip_bf16.h>
#include <stdint.h>

#define SEQ 4096
#define HID 1152
#define NH  16
#define HD  72
#define N3  3456
#define DQ  80        // Q padded head dim (5 x 16)
#define QBLK 256      // q rows per block (8 waves x 32)
#define TILE_B 25728  // tile bytes: K 64x256B = 16384, V 73x128B = 9344
#define TILE_E 12864  // tile elems
#define VBASE 16384   // V image byte offset within tile
#define ZOFF  77184   // static 16B zero block (after 3 buffers)

typedef __bf16 bf16;
typedef __bf16 bf16x8 __attribute__((ext_vector_type(8)));
typedef float  f32x4  __attribute__((ext_vector_type(4)));
typedef float  f32x16 __attribute__((ext_vector_type(16)));
typedef uint32_t u32x4 __attribute__((ext_vector_type(4)));

#define EXP2F(x) __builtin_amdgcn_exp2f(x)
#define PLSWAP(a, b) asm("v_permlane32_swap_b32 %0, %1" : "+v"(a), "+v"(b))

__device__ __forceinline__ void gload_lds16(const void* g, void* l) {
    __builtin_amdgcn_global_load_lds(
        (__attribute__((address_space(1))) void*)(void*)g,
        (__attribute__((address_space(3))) void*)l, 16, 0, 0);
}
__device__ __forceinline__ uint16_t bfbits(float x) {
    return __builtin_bit_cast(uint16_t, (bf16)x);
}

// ---------------- fused prep: hidden f32->bf16 + both weight transposes ----------------
// blocks [0,2304): cvt; [2304,6192): Wqkv^T; [6192,7488): Wproj^T
__global__ __launch_bounds__(256)
void prep(const float* __restrict__ hidden, const float* __restrict__ Wqkv,
          const float* __restrict__ Wproj, bf16* __restrict__ hid_b,
          bf16* __restrict__ WqkvT, bf16* __restrict__ WprojT)
{
    __shared__ float tl[32][33];
    int b = blockIdx.x, tid = threadIdx.x;
    if (b < 2304) {
        int i = b * 256 + tid;
        const float4* p = (const float4*)hidden + (size_t)i * 2;
        float4 a = p[0], c = p[1];
        bf16x8 o;
        o[0]=(bf16)a.x; o[1]=(bf16)a.y; o[2]=(bf16)a.z; o[3]=(bf16)a.w;
        o[4]=(bf16)c.x; o[5]=(bf16)c.y; o[6]=(bf16)c.z; o[7]=(bf16)c.w;
        ((bf16x8*)hid_b)[i] = o;
        return;
    }
    const float* in; bf16* out; int R, C, c0, r0;
    if (b < 6192) {
        int bb = b - 2304;
        in = Wqkv; out = WqkvT; R = HID; C = N3;
        c0 = (bb % 108) * 32; r0 = (bb / 108) * 32;
    } else {
        int bb = b - 6192;
        in = Wproj; out = WprojT; R = HID; C = HID;
        c0 = (bb % 36) * 32; r0 = (bb / 36) * 32;
    }
    int tx = tid & 31, ty = tid >> 5;
#pragma unroll
    for (int i = 0; i < 4; ++i)
        tl[ty + 8*i][tx] = in[(size_t)(r0 + ty + 8*i) * C + c0 + tx];
    __syncthreads();
#pragma unroll
    for (int i = 0; i < 4; ++i)
        out[(size_t)(c0 + ty + 8*i) * R + r0 + tx] = (bf16)tl[tx][ty + 8*i];
}

// ---------------- GEMM: C[M][N] = A[M][K] * BT[N][K]^T + bias ----------------
// BM=256 x BN=128, BK=64, 8 waves (4m x 2n of 64x64), 512 threads. Same
// source-baked XOR swizzle; m-stripe-per-XCD mapping (gridDim.x = 16 m-tiles).
// 48KB LDS -> 3 blocks/CU; 187 B staged per MFMA (vs 256 at 128^2) halves the
// per-output barrier/drain tax that BK=64 already proved is the marginal cost.
template<int OUT_F32>
__global__ __launch_bounds__(512)
void gemm_bt(const bf16* __restrict__ A, const bf16* __restrict__ BT,
             const float* __restrict__ bias, void* __restrict__ out,
             int M, int N, int K)
{
    __shared__ __align__(16) bf16 As[256 * 64];
    __shared__ __align__(16) bf16 Bs[128 * 64];
    int tid = threadIdx.x;
    int lane = tid & 63, w = tid >> 6;
    int wm = w & 3, wn = w >> 2;
    int orig = blockIdx.y * gridDim.x + blockIdx.x;
    int xcd = orig & 7, v = orig >> 3;
    int mpx = gridDim.x >> 3;                 // m-tiles per XCD (=2)
    int m0 = (xcd * mpx + (v % mpx)) * 256;
    int n0 = (v / mpx) * 128;
    int lq = lane & 15, lk = lane >> 4;

    int kx0 = ((lk ^ (lq & 7)) << 4);
    int kx1 = (((4 + lk) ^ (lq & 7)) << 4);

    f32x4 acc[4][4] = {};

    for (int k0 = 0; k0 < K; k0 += 64) {
        __syncthreads();
#pragma unroll
        for (int j = 0; j < 6; ++j) {
            int c = j * 512 + tid;              // A: 2048 chunks, B: 1024 chunks
            if (j < 4) {
                int row = c >> 3, kc = c & 7;
                gload_lds16(A + (size_t)(m0 + row) * K + k0 + ((kc ^ (row & 7)) << 3),
                            (char*)As + c * 16);
            } else {
                int c2 = c - 2048;
                int row = c2 >> 3, kc = c2 & 7;
                gload_lds16(BT + (size_t)(n0 + row) * K + k0 + ((kc ^ (row & 7)) << 3),
                            (char*)Bs + c2 * 16);
            }
        }
        __syncthreads();
#pragma unroll
        for (int ks = 0; ks < 2; ++ks) {
            int kx = ks ? kx1 : kx0;
            bf16x8 af[4], bfr[4];
#pragma unroll
            for (int m = 0; m < 4; ++m)
                af[m] = *(const bf16x8*)((char*)As + (wm * 64 + m * 16 + lq) * 128 + kx);
#pragma unroll
            for (int n = 0; n < 4; ++n)
                bfr[n] = *(const bf16x8*)((char*)Bs + (wn * 64 + n * 16 + lq) * 128 + kx);
#pragma unroll
            for (int m = 0; m < 4; ++m)
#pragma unroll
                for (int n = 0; n < 4; ++n)
                    acc[m][n] = __builtin_amdgcn_mfma_f32_16x16x32_bf16(af[m], bfr[n], acc[m][n], 0, 0, 0);
        }
    }

    int rb = m0 + wm * 64, cb = n0 + wn * 64;
#pragma unroll
    for (int m = 0; m < 4; ++m) {
#pragma unroll
        for (int n = 0; n < 4; ++n) {
            int col = cb + n * 16 + lq;
            float b = bias[col];
#pragma unroll
            for (int r = 0; r < 4; ++r) {
                int row = rb + m * 16 + lk * 4 + r;
                float v2 = acc[m][n][r] + b;
                if (OUT_F32) ((float*)out)[(size_t)row * N + col] = v2;
                else         ((bf16*)out)[(size_t)row * N + col] = (bf16)v2;
            }
        }
    }
}

// ---------------- fused pack: RoPE Q/K + V-transpose into KVp tile images ----------------
// blocks [0,20480): rope over NH*SEQ*80; [20480,21504): V pack.
// KVp[h][t][12864]: elems 0..8191 = K image, 64 keys x 128 elems (256B rows),
// data chunk dchunk (0..9) at physical pos dchunk^(key&15); the other 6
// positions per row are never read. elems 8192..12863 = V image, 73 rows x
// 64 elems (d 0..71 data, 72 = ones for l); pos cpos holds keys (cpos^(d&7))*8..
__global__ __launch_bounds__(256)
void pack(const bf16* __restrict__ qkv, const float* __restrict__ cs,
          const float* __restrict__ sn, bf16* __restrict__ Qp,
          bf16* __restrict__ KVp)
{
    __shared__ __align__(16) bf16 tl[64][80];
    int b = blockIdx.x, tid = threadIdx.x;
    if (b < 20480) {
        int idx = b * 256 + tid;                 // NH*SEQ*80
        int dd = idx % 80;
        int rest = idx / 80;
        int s = rest & (SEQ - 1), h = rest >> 12;
        float qv = 0.f, kv = 0.f;
        if (dd < HD) {
            const bf16* row = qkv + (size_t)s * N3 + h * HD;
            float c  = cs[s * HD + dd], si = sn[s * HD + dd];
            int   dp = (dd < 36) ? dd + 36 : dd - 36;
            float sg = (dd < 36) ? -1.f : 1.f;
            float qa = (float)row[dd],       qb = (float)row[dp];
            float ka = (float)row[HID + dd], kb = (float)row[HID + dp];
            qv = (qa * c + sg * qb * si) * (0.11785113019775793f * 1.4426950408889634f);
            kv =  ka * c + sg * kb * si;
        }
        int t = s >> 6, key = s & 63;
        int chunk = key * 16 + ((dd >> 3) ^ (key & 15));
        KVp[((size_t)(h * 64 + t)) * TILE_E + chunk * 8 + (dd & 7)] = (bf16)kv;
        Qp[((size_t)h * SEQ + s) * DQ + dd] = (bf16)qv;
        return;
    }
    int bb = b - 20480;
    int t = bb & 63, h = bb >> 6, s0 = t * 64;
    for (int i = tid; i < 64 * 9; i += 256) {
        int key = i / 9, c8 = (i % 9) * 8;
        *(bf16x8*)&tl[key][c8] =
            *(const bf16x8*)&qkv[(size_t)(s0 + key) * N3 + 2 * HID + h * HD + c8];
    }
    __syncthreads();
    bf16* dst = KVp + ((size_t)(h * 64 + t)) * TILE_E + 8192;
    for (int vcid = tid; vcid < 584; vcid += 256) {     // 73 rows x 8 chunks
        int d = vcid >> 3, cpos = vcid & 7;
        int kb8 = (cpos ^ (d & 7)) << 3;
        bf16x8 v;
#pragma unroll
        for (int j = 0; j < 8; ++j)
            v[j] = (d < HD) ? tl[kb8 + j][d] : (bf16)1.f;   // d==72: ones row
        *(bf16x8*)&dst[vcid * 8] = v;
    }
}

// ---- flash attention: 8 waves x 32q, 3-buffer rotation (R19/R20's attn_fwd14) ----
__global__ __launch_bounds__(512, 2)
void attn_fwd14(const bf16* __restrict__ Qp, const bf16* __restrict__ KVp,
                bf16* __restrict__ Oout)
{
    __shared__ __align__(16) char smem[77312];   // 3 x 25728 + zero block

    const int o = blockIdx.x;
    const int x = o & 7, s = o >> 3;
    const int h  = x * 2 + (s >> 4);
    const int q0 = (s & 15) * QBLK;
    const int tid = threadIdx.x, lane = tid & 63, w = tid >> 6;
    const int ql = lane & 31, hi = lane >> 5;
    const int q  = q0 + w * 32 + ql;

    bf16x8 qf[5];
    const bf16* qbase = Qp + ((size_t)h * SEQ + q) * DQ + hi * 8;
#pragma unroll
    for (int ks = 0; ks < 5; ++ks) qf[ks] = *(const bf16x8*)(qbase + ks * 16);

    int aK[5];
#pragma unroll
    for (int ks = 0; ks < 5; ++ks)
        aK[ks] = ql * 256 + (((ks * 2 + hi) ^ (ql & 15)) * 16);
    int aV[4];
#pragma unroll
    for (int u = 0; u < 4; ++u)
        aV[u] = VBASE + ql * 128 + (((u * 2 + hi) ^ (ql & 7)) * 16);

    f32x16 o_[3] = {};           // O^T accum; V row 72 (ones) carries l

    const bf16* kvh = KVp + (size_t)h * (64 * TILE_E);

#define STAGE(T, DB) do {                                                      \
        const bf16* s_ = kvh + (size_t)(T) * TILE_E;                           \
        _Pragma("unroll")                                                      \
        for (int j_ = 0; j_ < 4; ++j_) {                                       \
            int c_ = j_ * 512 + tid;                                           \
            if (c_ < 1608) gload_lds16(s_ + c_ * 8, smem + (DB) + c_ * 16);    \
        }                                                                      \
    } while (0)

    auto qk = [&](const char* bK, f32x16& sa, f32x16& sb) {
        __builtin_amdgcn_s_setprio(1);
#pragma unroll
        for (int ks = 0; ks < 5; ++ks) {
            bf16x8 kf = *(const bf16x8*)(bK + aK[ks]);
            sa = __builtin_amdgcn_mfma_f32_32x32x16_bf16(kf, qf[ks], sa, 0, 0, 0);
        }
#pragma unroll
        for (int ks = 0; ks < 5; ++ks) {
            bf16x8 kf = *(const bf16x8*)(bK + 8192 + aK[ks]);   // keys 32..63
            sb = __builtin_amdgcn_mfma_f32_32x32x16_bf16(kf, qf[ks], sb, 0, 0, 0);
        }
        __builtin_amdgcn_s_setprio(0);
    };

    auto expv = [&](const f32x16& sa, const f32x16& sb, const char* bV) {
        uint32_t wd[16];
#pragma unroll
        for (int i = 0; i < 8; ++i) {
            wd[i]   = (uint32_t)bfbits(EXP2F(sa[2*i])) | ((uint32_t)bfbits(EXP2F(sa[2*i+1])) << 16);
            wd[8+i] = (uint32_t)bfbits(EXP2F(sb[2*i])) | ((uint32_t)bfbits(EXP2F(sb[2*i+1])) << 16);
        }
        PLSWAP(wd[0], wd[2]);   PLSWAP(wd[1], wd[3]);
        PLSWAP(wd[4], wd[6]);   PLSWAP(wd[5], wd[7]);
        PLSWAP(wd[8], wd[10]);  PLSWAP(wd[9], wd[11]);
        PLSWAP(wd[12], wd[14]); PLSWAP(wd[13], wd[15]);
        u32x4 u0 = {wd[0],wd[1],wd[2],wd[3]},   u1 = {wd[4],wd[5],wd[6],wd[7]};
        u32x4 u2 = {wd[8],wd[9],wd[10],wd[11]}, u3 = {wd[12],wd[13],wd[14],wd[15]};
        bf16x8 pb[4] = { __builtin_bit_cast(bf16x8, u0), __builtin_bit_cast(bf16x8, u1),
                         __builtin_bit_cast(bf16x8, u2), __builtin_bit_cast(bf16x8, u3) };
        __builtin_amdgcn_s_setprio(1);
#pragma unroll
        for (int db = 0; db < 3; ++db)
#pragma unroll
            for (int u = 0; u < 4; ++u) {
                const char* pv;
                if (db < 2)          pv = bV + db * 4096 + aV[u];
                else if (ql <= 8)    pv = bV + 8192 + aV[u];      // rows 64..72
                else                 pv = smem + ZOFF;            // zero pad rows
                bf16x8 vf = *(const bf16x8*)pv;
                o_[db] = __builtin_amdgcn_mfma_f32_32x32x16_bf16(vf, pb[u], o_[db], 0, 0, 0);
            }
        __builtin_amdgcn_s_setprio(0);
    };

    f32x16 pa = {}, pb_ = {};    // previous tile's scores (pipeline state)

    if (tid < 4) ((float*)(smem + ZOFF))[tid] = 0.f;
    STAGE(0, 0);
    asm volatile("s_waitcnt vmcnt(0) lgkmcnt(0)" ::: "memory");
    __builtin_amdgcn_s_barrier();
    STAGE(1, TILE_B);
    qk(smem, pa, pb_);
    asm volatile("s_waitcnt vmcnt(0)" ::: "memory");
    __builtin_amdgcn_s_barrier();

#define BODY(T, KB, VB, SB) do {                                               \
        if ((T) < 63) STAGE((T) + 1, SB);                                      \
        f32x16 ca = {}, cb = {};                                               \
        qk(smem + (KB), ca, cb);                                               \
        expv(pa, pb_, smem + (VB));                                            \
        pa = ca; pb_ = cb;                                                     \
        __builtin_amdgcn_sched_barrier(0);                                     \
        asm volatile("s_waitcnt vmcnt(0)" ::: "memory");                       \
        __builtin_amdgcn_s_barrier();                                          \
    } while (0)

    for (int t = 1; t < 64; t += 3) {
        BODY(t,     TILE_B,     0,          2 * TILE_B);
        BODY(t + 1, 2 * TILE_B, TILE_B,     0);
        BODY(t + 2, 0,          2 * TILE_B, TILE_B);
    }
    expv(pa, pb_, smem);         // drain: tile 63 (V resident in buffer 0)
#undef BODY
#undef STAGE

    // ---- epilogue: LDS transpose (stride 82 = 41 words, odd -> conflict-free) ----
    __syncthreads();
    bf16* Os = (bf16*)smem;                        // [QBLK][82]
    {
        float lv  = o_[2][4];                      // d=72 row holds l (hi=0 lanes)
        float lo_ = __shfl_xor(lv, 32);
        float invl = 1.0f / (hi ? lo_ : lv);
        int qloc = w * 32 + ql;
#pragma unroll
        for (int db = 0; db < 3; ++db)
#pragma unroll
            for (int r = 0; r < 16; ++r) {
                int dloc = (r & 3) + 8 * (r >> 2) + 4 * hi;
                int d = db * 32 + dloc;
                if (d < HD) Os[qloc * 82 + d] = (bf16)(o_[db][r] * invl);
            }
    }
    __syncthreads();
    for (int i = tid; i < QBLK * 36; i += 512) {
        int row = i / 36, c = i % 36;
        uint32_t val = *(const uint32_t*)((const char*)Os + row * 164 + c * 4);
        *(uint32_t*)((char*)Oout + (size_t)(q0 + row) * 2304 + h * 144 + c * 4) = val;
    }
}

extern "C" void kernel_launch(void* const* d_in, const int* in_sizes, int n_in,
                              void* d_out, int out_size, void* d_ws, size_t ws_size,
                              hipStream_t stream)
{
    const float* hidden = (const float*)d_in[0];
    // d_in[1] = cu_seqlens: unused by the reference
    const float* cosT  = (const float*)d_in[2];
    const float* sinT  = (const float*)d_in[3];
    const float* Wqkv  = (const float*)d_in[4];
    const float* bqkv  = (const float*)d_in[5];
    const float* Wproj = (const float*)d_in[6];
    const float* bproj = (const float*)d_in[7];

    char* ws = (char*)d_ws;
    size_t off = 0;
    auto alloc = [&](size_t bytes) {
        char* p = ws + off;
        off += (bytes + 255) & ~(size_t)255;
        return p;
    };
    bf16* hid_b  = (bf16*)alloc((size_t)SEQ * HID * 2);
    bf16* WqkvT  = (bf16*)alloc((size_t)N3  * HID * 2);
    bf16* WprojT = (bf16*)alloc((size_t)HID * HID * 2);
    bf16* qkv_b  = (bf16*)alloc((size_t)SEQ * N3  * 2);
    bf16* Qp     = (bf16*)alloc((size_t)NH * SEQ * DQ * 2);
    bf16* KVp    = (bf16*)alloc((size_t)NH * 64 * TILE_E * 2);
    bf16* attno  = hid_b;  // overlay: hid_b dead after GEMM1

    prep<<<7488, 256, 0, stream>>>(hidden, Wqkv, Wproj, hid_b, WqkvT, WprojT);
    gemm_bt<0><<<dim3(SEQ / 256, N3 / 128), 512, 0, stream>>>(hid_b, WqkvT, bqkv, qkv_b,
                                                              SEQ, N3, HID);
    pack<<<21504, 256, 0, stream>>>(qkv_b, cosT, sinT, Qp, KVp);
    attn_fwd14<<<dim3(SEQ / QBLK * NH), 512, 0, stream>>>(Qp, KVp, attno);
    gemm_bt<1><<<dim3(SEQ / 256, HID / 128), 512, 0, stream>>>(attno, WprojT, bproj, d_out,
                                                               SEQ, HID, HID);
}

// Round 23
// 179.953 us; speedup vs baseline: 1.1241x; 1.0250x over previous
//
#include <hip/hip_runtime.h>
#include <hip/hip_bf16.h>
#include <stdint.h>

#define SEQ 4096
#define HID 1152
#define NH  16
#define HD  72
#define N3  3456
#define DQ  80        // Q padded head dim (5 x 16)
#define QBLK 256      // q rows per block (8 waves x 32)
#define TILE_B 25728  // tile bytes: K 64x256B = 16384, V 73x128B = 9344
#define TILE_E 12864  // tile elems
#define VBASE 16384   // V image byte offset within tile
#define ZOFF  77184   // static 16B zero block (after 3 buffers)
#define QSCALE (0.11785113019775793f * 1.4426950408889634f)   // 72^-0.5 * log2e

typedef __bf16 bf16;
typedef __bf16 bf16x4 __attribute__((ext_vector_type(4)));
typedef __bf16 bf16x8 __attribute__((ext_vector_type(8)));
typedef float  f32x4  __attribute__((ext_vector_type(4)));
typedef float  f32x16 __attribute__((ext_vector_type(16)));
typedef uint32_t u32x4 __attribute__((ext_vector_type(4)));

#define EXP2F(x) __builtin_amdgcn_exp2f(x)
#define PLSWAP(a, b) asm("v_permlane32_swap_b32 %0, %1" : "+v"(a), "+v"(b))

__device__ __forceinline__ void gload_lds16(const void* g, void* l) {
    __builtin_amdgcn_global_load_lds(
        (__attribute__((address_space(1))) void*)(void*)g,
        (__attribute__((address_space(3))) void*)l, 16, 0, 0);
}
__device__ __forceinline__ uint16_t bfbits(float x) {
    return __builtin_bit_cast(uint16_t, (bf16)x);
}

// ---------------- fused prep: hidden f32->bf16 + both weight transposes ----------------
// blocks [0,2304): cvt; [2304,6192): Wqkv^T; [6192,7488): Wproj^T
__global__ __launch_bounds__(256)
void prep(const float* __restrict__ hidden, const float* __restrict__ Wqkv,
          const float* __restrict__ Wproj, bf16* __restrict__ hid_b,
          bf16* __restrict__ WqkvT, bf16* __restrict__ WprojT)
{
    __shared__ float tl[32][33];
    int b = blockIdx.x, tid = threadIdx.x;
    if (b < 2304) {
        int i = b * 256 + tid;
        const float4* p = (const float4*)hidden + (size_t)i * 2;
        float4 a = p[0], c = p[1];
        bf16x8 o;
        o[0]=(bf16)a.x; o[1]=(bf16)a.y; o[2]=(bf16)a.z; o[3]=(bf16)a.w;
        o[4]=(bf16)c.x; o[5]=(bf16)c.y; o[6]=(bf16)c.z; o[7]=(bf16)c.w;
        ((bf16x8*)hid_b)[i] = o;
        return;
    }
    const float* in; bf16* out; int R, C, c0, r0;
    if (b < 6192) {
        int bb = b - 2304;
        in = Wqkv; out = WqkvT; R = HID; C = N3;
        c0 = (bb % 108) * 32; r0 = (bb / 108) * 32;
    } else {
        int bb = b - 6192;
        in = Wproj; out = WprojT; R = HID; C = HID;
        c0 = (bb % 36) * 32; r0 = (bb / 36) * 32;
    }
    int tx = tid & 31, ty = tid >> 5;
#pragma unroll
    for (int i = 0; i < 4; ++i)
        tl[ty + 8*i][tx] = in[(size_t)(r0 + ty + 8*i) * C + c0 + tx];
    __syncthreads();
#pragma unroll
    for (int i = 0; i < 4; ++i)
        out[(size_t)(c0 + ty + 8*i) * R + r0 + tx] = (bf16)tl[tx][ty + 8*i];
}

// ---------------- GEMM: C[M][N] = A[M][K] * BT[N][K]^T + bias ----------------
// BM=256 x BN=128, BK=64, 8 waves (4m x 2n), 512 threads (R21 config).
template<int OUT_F32>
__global__ __launch_bounds__(512)
void gemm_bt(const bf16* __restrict__ A, const bf16* __restrict__ BT,
             const float* __restrict__ bias, void* __restrict__ out,
             int M, int N, int K)
{
    __shared__ __align__(16) bf16 As[256 * 64];
    __shared__ __align__(16) bf16 Bs[128 * 64];
    int tid = threadIdx.x;
    int lane = tid & 63, w = tid >> 6;
    int wm = w & 3, wn = w >> 2;
    int orig = blockIdx.y * gridDim.x + blockIdx.x;
    int xcd = orig & 7, v = orig >> 3;
    int mpx = gridDim.x >> 3;
    int m0 = (xcd * mpx + (v % mpx)) * 256;
    int n0 = (v / mpx) * 128;
    int lq = lane & 15, lk = lane >> 4;

    int kx0 = ((lk ^ (lq & 7)) << 4);
    int kx1 = (((4 + lk) ^ (lq & 7)) << 4);

    f32x4 acc[4][4] = {};

    for (int k0 = 0; k0 < K; k0 += 64) {
        __syncthreads();
#pragma unroll
        for (int j = 0; j < 6; ++j) {
            int c = j * 512 + tid;
            if (j < 4) {
                int row = c >> 3, kc = c & 7;
                gload_lds16(A + (size_t)(m0 + row) * K + k0 + ((kc ^ (row & 7)) << 3),
                            (char*)As + c * 16);
            } else {
                int c2 = c - 2048;
                int row = c2 >> 3, kc = c2 & 7;
                gload_lds16(BT + (size_t)(n0 + row) * K + k0 + ((kc ^ (row & 7)) << 3),
                            (char*)Bs + c2 * 16);
            }
        }
        __syncthreads();
#pragma unroll
        for (int ks = 0; ks < 2; ++ks) {
            int kx = ks ? kx1 : kx0;
            bf16x8 af[4], bfr[4];
#pragma unroll
            for (int m = 0; m < 4; ++m)
                af[m] = *(const bf16x8*)((char*)As + (wm * 64 + m * 16 + lq) * 128 + kx);
#pragma unroll
            for (int n = 0; n < 4; ++n)
                bfr[n] = *(const bf16x8*)((char*)Bs + (wn * 64 + n * 16 + lq) * 128 + kx);
#pragma unroll
            for (int m = 0; m < 4; ++m)
#pragma unroll
                for (int n = 0; n < 4; ++n)
                    acc[m][n] = __builtin_amdgcn_mfma_f32_16x16x32_bf16(af[m], bfr[n], acc[m][n], 0, 0, 0);
        }
    }

    int rb = m0 + wm * 64, cb = n0 + wn * 64;
#pragma unroll
    for (int m = 0; m < 4; ++m) {
#pragma unroll
        for (int n = 0; n < 4; ++n) {
            int col = cb + n * 16 + lq;
            float b = bias[col];
#pragma unroll
            for (int r = 0; r < 4; ++r) {
                int row = rb + m * 16 + lk * 4 + r;
                float v2 = acc[m][n][r] + b;
                if (OUT_F32) ((float*)out)[(size_t)row * N + col] = v2;
                else         ((bf16*)out)[(size_t)row * N + col] = (bf16)v2;
            }
        }
    }
}

// ---------------- fused pack: vectorized RoPE Q/K + V-transpose ----------------
// blocks [0,5120): rope over NH*SEQ*20 4-dim chunks; [5120,6144): V pack.
// 4-dim chunks never straddle the +-36 rotate-half boundary (36 % 4 == 0).
// K image element address = key*128 + pos*8 + (dd0&7), pos = dchunk^(key&15)
// (R22 bug: key*128 row offset was dropped).
__global__ __launch_bounds__(256)
void pack(const bf16* __restrict__ qkv, const float* __restrict__ cs,
          const float* __restrict__ sn, bf16* __restrict__ Qp,
          bf16* __restrict__ KVp)
{
    __shared__ __align__(16) bf16 tl[64][80];
    int b = blockIdx.x, tid = threadIdx.x;
    if (b < 5120) {
        int idx = b * 256 + tid;                 // NH*SEQ*20
        int c20 = idx % 20;
        int rest = idx / 20;
        int s = rest & (SEQ - 1), h = rest >> 12;
        int key = s & 63, t = s >> 6;
        int dd0 = c20 * 4;
        bf16* qdst = Qp + ((size_t)h * SEQ + s) * DQ + dd0;
        bf16* krow = KVp + ((size_t)(h * 64 + t)) * TILE_E + key * 128;
        if (c20 >= 18) {                         // pad dims 72..79: zeros
            bf16x4 z = {};
            *(bf16x4*)qdst = z;
            int pos = 9 ^ (key & 15);
            *(bf16x4*)&krow[pos * 8 + (c20 & 1) * 4] = z;
            return;
        }
        int  po = (dd0 < 36) ? 36 : -36;
        float sg = (dd0 < 36) ? -1.f : 1.f;
        const bf16* row = qkv + (size_t)s * N3 + h * HD + dd0;
        bf16x4 q4  = *(const bf16x4*)row;
        bf16x4 qp4 = *(const bf16x4*)(row + po);
        bf16x4 k4  = *(const bf16x4*)(row + HID);
        bf16x4 kp4 = *(const bf16x4*)(row + HID + po);
        f32x4  c4  = *(const f32x4*)(cs + s * HD + dd0);
        f32x4  s4  = *(const f32x4*)(sn + s * HD + dd0);
        bf16x4 qo, ko;
#pragma unroll
        for (int j = 0; j < 4; ++j) {
            qo[j] = (bf16)(((float)q4[j] * c4[j] + sg * (float)qp4[j] * s4[j]) * QSCALE);
            ko[j] = (bf16)( (float)k4[j] * c4[j] + sg * (float)kp4[j] * s4[j]);
        }
        *(bf16x4*)qdst = qo;
        int pos = (c20 >> 1) ^ (key & 15);
        *(bf16x4*)&krow[pos * 8 + (c20 & 1) * 4] = ko;
        return;
    }
    int bb = b - 5120;
    int t = bb & 63, h = bb >> 6, s0 = t * 64;
    for (int i = tid; i < 64 * 9; i += 256) {
        int key = i / 9, c8 = (i % 9) * 8;
        *(bf16x8*)&tl[key][c8] =
            *(const bf16x8*)&qkv[(size_t)(s0 + key) * N3 + 2 * HID + h * HD + c8];
    }
    __syncthreads();
    bf16* dst = KVp + ((size_t)(h * 64 + t)) * TILE_E + 8192;
    for (int vcid = tid; vcid < 584; vcid += 256) {     // 73 rows x 8 chunks
        int d = vcid >> 3, cpos = vcid & 7;
        int kb8 = (cpos ^ (d & 7)) << 3;
        bf16x8 v;
#pragma unroll
        for (int j = 0; j < 8; ++j)
            v[j] = (d < HD) ? tl[kb8 + j][d] : (bf16)1.f;   // d==72: ones row
        *(bf16x8*)&dst[vcid * 8] = v;
    }
}

// ---- flash attention: 8 waves x 32q, 3-buffer rotation (R19-R21's attn_fwd14) ----
__global__ __launch_bounds__(512, 2)
void attn_fwd14(const bf16* __restrict__ Qp, const bf16* __restrict__ KVp,
                bf16* __restrict__ Oout)
{
    __shared__ __align__(16) char smem[77312];   // 3 x 25728 + zero block

    const int o = blockIdx.x;
    const int x = o & 7, s = o >> 3;
    const int h  = x * 2 + (s >> 4);
    const int q0 = (s & 15) * QBLK;
    const int tid = threadIdx.x, lane = tid & 63, w = tid >> 6;
    const int ql = lane & 31, hi = lane >> 5;
    const int q  = q0 + w * 32 + ql;

    bf16x8 qf[5];
    const bf16* qbase = Qp + ((size_t)h * SEQ + q) * DQ + hi * 8;
#pragma unroll
    for (int ks = 0; ks < 5; ++ks) qf[ks] = *(const bf16x8*)(qbase + ks * 16);

    int aK[5];
#pragma unroll
    for (int ks = 0; ks < 5; ++ks)
        aK[ks] = ql * 256 + (((ks * 2 + hi) ^ (ql & 15)) * 16);
    int aV[4];
#pragma unroll
    for (int u = 0; u < 4; ++u)
        aV[u] = VBASE + ql * 128 + (((u * 2 + hi) ^ (ql & 7)) * 16);

    f32x16 o_[3] = {};           // O^T accum; V row 72 (ones) carries l

    const bf16* kvh = KVp + (size_t)h * (64 * TILE_E);

#define STAGE(T, DB) do {                                                      \
        const bf16* s_ = kvh + (size_t)(T) * TILE_E;                           \
        _Pragma("unroll")                                                      \
        for (int j_ = 0; j_ < 4; ++j_) {                                       \
            int c_ = j_ * 512 + tid;                                           \
            if (c_ < 1608) gload_lds16(s_ + c_ * 8, smem + (DB) + c_ * 16);    \
        }                                                                      \
    } while (0)

    auto qk = [&](const char* bK, f32x16& sa, f32x16& sb) {
        __builtin_amdgcn_s_setprio(1);
#pragma unroll
        for (int ks = 0; ks < 5; ++ks) {
            bf16x8 kf = *(const bf16x8*)(bK + aK[ks]);
            sa = __builtin_amdgcn_mfma_f32_32x32x16_bf16(kf, qf[ks], sa, 0, 0, 0);
        }
#pragma unroll
        for (int ks = 0; ks < 5; ++ks) {
            bf16x8 kf = *(const bf16x8*)(bK + 8192 + aK[ks]);   // keys 32..63
            sb = __builtin_amdgcn_mfma_f32_32x32x16_bf16(kf, qf[ks], sb, 0, 0, 0);
        }
        __builtin_amdgcn_s_setprio(0);
    };

    auto expv = [&](const f32x16& sa, const f32x16& sb, const char* bV) {
        uint32_t wd[16];
#pragma unroll
        for (int i = 0; i < 8; ++i) {
            wd[i]   = (uint32_t)bfbits(EXP2F(sa[2*i])) | ((uint32_t)bfbits(EXP2F(sa[2*i+1])) << 16);
            wd[8+i] = (uint32_t)bfbits(EXP2F(sb[2*i])) | ((uint32_t)bfbits(EXP2F(sb[2*i+1])) << 16);
        }
        PLSWAP(wd[0], wd[2]);   PLSWAP(wd[1], wd[3]);
        PLSWAP(wd[4], wd[6]);   PLSWAP(wd[5], wd[7]);
        PLSWAP(wd[8], wd[10]);  PLSWAP(wd[9], wd[11]);
        PLSWAP(wd[12], wd[14]); PLSWAP(wd[13], wd[15]);
        u32x4 u0 = {wd[0],wd[1],wd[2],wd[3]},   u1 = {wd[4],wd[5],wd[6],wd[7]};
        u32x4 u2 = {wd[8],wd[9],wd[10],wd[11]}, u3 = {wd[12],wd[13],wd[14],wd[15]};
        bf16x8 pb[4] = { __builtin_bit_cast(bf16x8, u0), __builtin_bit_cast(bf16x8, u1),
                         __builtin_bit_cast(bf16x8, u2), __builtin_bit_cast(bf16x8, u3) };
        __builtin_amdgcn_s_setprio(1);
#pragma unroll
        for (int db = 0; db < 3; ++db)
#pragma unroll
            for (int u = 0; u < 4; ++u) {
                const char* pv;
                if (db < 2)          pv = bV + db * 4096 + aV[u];
                else if (ql <= 8)    pv = bV + 8192 + aV[u];      // rows 64..72
                else                 pv = smem + ZOFF;            // zero pad rows
                bf16x8 vf = *(const bf16x8*)pv;
                o_[db] = __builtin_amdgcn_mfma_f32_32x32x16_bf16(vf, pb[u], o_[db], 0, 0, 0);
            }
        __builtin_amdgcn_s_setprio(0);
    };

    f32x16 pa = {}, pb_ = {};    // previous tile's scores (pipeline state)

    if (tid < 4) ((float*)(smem + ZOFF))[tid] = 0.f;
    STAGE(0, 0);
    asm volatile("s_waitcnt vmcnt(0) lgkmcnt(0)" ::: "memory");
    __builtin_amdgcn_s_barrier();
    STAGE(1, TILE_B);
    qk(smem, pa, pb_);
    asm volatile("s_waitcnt vmcnt(0)" ::: "memory");
    __builtin_amdgcn_s_barrier();

#define BODY(T, KB, VB, SB) do {                                               \
        if ((T) < 63) STAGE((T) + 1, SB);                                      \
        f32x16 ca = {}, cb = {};                                               \
        qk(smem + (KB), ca, cb);                                               \
        expv(pa, pb_, smem + (VB));                                            \
        pa = ca; pb_ = cb;                                                     \
        __builtin_amdgcn_sched_barrier(0);                                     \
        asm volatile("s_waitcnt vmcnt(0)" ::: "memory");                       \
        __builtin_amdgcn_s_barrier();                                          \
    } while (0)

    for (int t = 1; t < 64; t += 3) {
        BODY(t,     TILE_B,     0,          2 * TILE_B);
        BODY(t + 1, 2 * TILE_B, TILE_B,     0);
        BODY(t + 2, 0,          2 * TILE_B, TILE_B);
    }
    expv(pa, pb_, smem);         // drain: tile 63 (V resident in buffer 0)
#undef BODY
#undef STAGE

    // ---- epilogue: LDS transpose (stride 82 = 41 words, odd -> conflict-free) ----
    __syncthreads();
    bf16* Os = (bf16*)smem;                        // [QBLK][82]
    {
        float lv  = o_[2][4];                      // d=72 row holds l (hi=0 lanes)
        float lo_ = __shfl_xor(lv, 32);
        float invl = 1.0f / (hi ? lo_ : lv);
        int qloc = w * 32 + ql;
#pragma unroll
        for (int db = 0; db < 3; ++db)
#pragma unroll
            for (int r = 0; r < 16; ++r) {
                int dloc = (r & 3) + 8 * (r >> 2) + 4 * hi;
                int d = db * 32 + dloc;
                if (d < HD) Os[qloc * 82 + d] = (bf16)(o_[db][r] * invl);
            }
    }
    __syncthreads();
    for (int i = tid; i < QBLK * 36; i += 512) {
        int row = i / 36, c = i % 36;
        uint32_t val = *(const uint32_t*)((const char*)Os + row * 164 + c * 4);
        *(uint32_t*)((char*)Oout + (size_t)(q0 + row) * 2304 + h * 144 + c * 4) = val;
    }
}

extern "C" void kernel_launch(void* const* d_in, const int* in_sizes, int n_in,
                              void* d_out, int out_size, void* d_ws, size_t ws_size,
                              hipStream_t stream)
{
    const float* hidden = (const float*)d_in[0];
    // d_in[1] = cu_seqlens: unused by the reference
    const float* cosT  = (const float*)d_in[2];
    const float* sinT  = (const float*)d_in[3];
    const float* Wqkv  = (const float*)d_in[4];
    const float* bqkv  = (const float*)d_in[5];
    const float* Wproj = (const float*)d_in[6];
    const float* bproj = (const float*)d_in[7];

    char* ws = (char*)d_ws;
    size_t off = 0;
    auto alloc = [&](size_t bytes) {
        char* p = ws + off;
        off += (bytes + 255) & ~(size_t)255;
        return p;
    };
    bf16* hid_b  = (bf16*)alloc((size_t)SEQ * HID * 2);
    bf16* WqkvT  = (bf16*)alloc((size_t)N3  * HID * 2);
    bf16* WprojT = (bf16*)alloc((size_t)HID * HID * 2);
    bf16* qkv_b  = (bf16*)alloc((size_t)SEQ * N3  * 2);
    bf16* Qp     = (bf16*)alloc((size_t)NH * SEQ * DQ * 2);
    bf16* KVp    = (bf16*)alloc((size_t)NH * 64 * TILE_E * 2);
    bf16* attno  = hid_b;  // overlay: hid_b dead after GEMM1

    prep<<<7488, 256, 0, stream>>>(hidden, Wqkv, Wproj, hid_b, WqkvT, WprojT);
    gemm_bt<0><<<dim3(SEQ / 256, N3 / 128), 512, 0, stream>>>(hid_b, WqkvT, bqkv, qkv_b,
                                                              SEQ, N3, HID);
    pack<<<6144, 256, 0, stream>>>(qkv_b, cosT, sinT, Qp, KVp);
    attn_fwd14<<<dim3(SEQ / QBLK * NH), 512, 0, stream>>>(Qp, KVp, attno);
    gemm_bt<1><<<dim3(SEQ / 256, HID / 128), 512, 0, stream>>>(attno, WprojT, bproj, d_out,
                                                               SEQ, HID, HID);
}